// Round 2
// baseline (433.925 us; speedup 1.0000x reference)
//
#include <hip/hip_runtime.h>
#include <hip/hip_bf16.h>

typedef __attribute__((ext_vector_type(8))) short bf16x8;
typedef __attribute__((ext_vector_type(4))) float f32x4;

#define SEQ 2048
#define DMODEL 1024
#define NH 16
#define HD 64
#define BATCH 4
#define BHTOT 64          // BATCH*NH
#define BS 8192           // BATCH*SEQ
#define QKV_ELEMS 8388608 // BS*DMODEL

// SCALE = 8 (sqrt(64)); softmax done in exp2 domain: C2 = (1/8)*log2(e)
#define C2EXP 0.1803368801111244f

__device__ __forceinline__ ushort f2bf(float f) {
  union { float f; unsigned u; } v; v.f = f;
  unsigned r = (v.u + 0x7FFFu + ((v.u >> 16) & 1u)) >> 16;
  return (ushort)r;
}

#if __has_builtin(__builtin_amdgcn_exp2f)
#define EXP2F(x) __builtin_amdgcn_exp2f(x)
#else
#define EXP2F(x) exp2f(x)
#endif

// ---------------- weight f32 -> bf16 convert ----------------
__global__ __launch_bounds__(256) void convert_w(
    const float* __restrict__ w0, const float* __restrict__ w1,
    const float* __restrict__ w2, ushort* __restrict__ out) {
  const float* src = blockIdx.y == 0 ? w0 : (blockIdx.y == 1 ? w1 : w2);
  size_t e = ((size_t)blockIdx.x * 256 + threadIdx.x) * 4;
  float4 v = *(const float4*)(src + e);
  ushort4 o = { f2bf(v.x), f2bf(v.y), f2bf(v.z), f2bf(v.w) };
  *(ushort4*)(out + (size_t)blockIdx.y * 1048576 + e) = o;
}

// ---------------- QKV projection GEMM ----------------
// out[m][n] = sum_k X[m][k] * W[n][k] + bias[n], stored bf16 in [B,H,S,HD]
__global__ __launch_bounds__(256) void qkv_gemm(
    const float* __restrict__ x0, const float* __restrict__ x1, const float* __restrict__ x2,
    const ushort* __restrict__ Wb,
    const float* __restrict__ bq, const float* __restrict__ bk, const float* __restrict__ bv,
    ushort* __restrict__ qkv) {
  __shared__ ushort sA[128][40];  // +8 pad: row stride 80B -> 2-way bank alias (free)
  __shared__ ushort sB[128][40];

  const int z = blockIdx.z;
  const float* X = z == 0 ? x0 : (z == 1 ? x1 : x2);
  const ushort* W = Wb + (size_t)z * 1048576;
  const float* bias = z == 0 ? bq : (z == 1 ? bk : bv);
  ushort* out = qkv + (size_t)z * QKV_ELEMS;

  const int t = threadIdx.x;
  const int m0 = blockIdx.x * 128;
  const int n0 = blockIdx.y * 128;
  const int w = t >> 6, l = t & 63, lr = l & 15, lhi = l >> 4;
  const int wr = (w >> 1) * 64, wc = (w & 1) * 64;

  f32x4 acc[4][4];
#pragma unroll
  for (int i = 0; i < 4; i++)
#pragma unroll
    for (int j = 0; j < 4; j++) acc[i][j] = (f32x4){0.f, 0.f, 0.f, 0.f};

  for (int k0 = 0; k0 < DMODEL; k0 += 32) {
#pragma unroll
    for (int i = 0; i < 4; i++) {
      int e = i * 256 + t;
      int row = e >> 3, col = (e & 7) * 4;
      float4 a = *(const float4*)(X + (size_t)(m0 + row) * DMODEL + k0 + col);
      ushort4 ab = { f2bf(a.x), f2bf(a.y), f2bf(a.z), f2bf(a.w) };
      *(ushort4*)(&sA[row][col]) = ab;
      ushort4 bb = *(const ushort4*)(W + (size_t)(n0 + row) * DMODEL + k0 + col);
      *(ushort4*)(&sB[row][col]) = bb;
    }
    __syncthreads();
    bf16x8 af[4], bfr[4];
#pragma unroll
    for (int mi = 0; mi < 4; mi++) af[mi] = *(const bf16x8*)(&sA[wr + mi * 16 + lr][lhi * 8]);
#pragma unroll
    for (int ni = 0; ni < 4; ni++) bfr[ni] = *(const bf16x8*)(&sB[wc + ni * 16 + lr][lhi * 8]);
#pragma unroll
    for (int mi = 0; mi < 4; mi++)
#pragma unroll
      for (int ni = 0; ni < 4; ni++)
        acc[mi][ni] = __builtin_amdgcn_mfma_f32_16x16x32_bf16(af[mi], bfr[ni], acc[mi][ni], 0, 0, 0);
    __syncthreads();
  }

  // epilogue: C layout col=lane&15, row=(lane>>4)*4+reg
#pragma unroll
  for (int mi = 0; mi < 4; mi++) {
#pragma unroll
    for (int ni = 0; ni < 4; ni++) {
      int col = n0 + wc + ni * 16 + lr;
      float bsv = bias[col];
      int h = col >> 6, hd = col & 63;
#pragma unroll
      for (int r = 0; r < 4; r++) {
        int row = m0 + wr + mi * 16 + lhi * 4 + r;
        int b = row >> 11, s = row & 2047;
        float vv = acc[mi][ni][r] + bsv;
        out[(((size_t)(b * NH + h)) * SEQ + s) * HD + hd] = f2bf(vv);
      }
    }
  }
}

// ---------------- flash attention ----------------
// qkv: bf16 [3][BH][SEQ][HD]; out: f32 [B,S,D]
__global__ __launch_bounds__(256) void attn_kernel(const ushort* __restrict__ qkv,
                                                   float* __restrict__ out) {
  __shared__ ushort Vt[2][64][72];   // double-buffered V^T tile: [hd][kv], stride 144B
  __shared__ ushort Pl[4][16][72];   // per-wave P tile: [qrow][kv], stride 144B

  const int bid = blockIdx.x;
  const int bh = bid >> 5, qt = bid & 31;
  const int q0 = qt * 64;
  const int t = threadIdx.x, w = t >> 6, l = t & 63, lr = l & 15, lhi = l >> 4;

  const ushort* q = qkv;
  const ushort* k = qkv + QKV_ELEMS;
  const ushort* v = qkv + 2 * (size_t)QKV_ELEMS;
  const size_t base = (size_t)bh * SEQ * HD;

  // staging coords: each thread loads 16B of one V row, writes a column run
  const int skv = t & 63;        // kv row this thread loads
  const int shb = (t >> 6) * 8;  // hd block base (0,8,16,24), +32 on 2nd iter

  // hoist Q fragments (A-frag: row=l&15, k=(l>>4)*8..+8)
  bf16x8 aq[2];
  {
    int qrow = q0 + w * 16 + lr;
#pragma unroll
    for (int kk = 0; kk < 2; kk++)
      aq[kk] = *(const bf16x8*)(q + base + (size_t)qrow * HD + kk * 32 + lhi * 8);
  }

  float m2[4], lsum[4];
  f32x4 acc_o[4];
#pragma unroll
  for (int r = 0; r < 4; r++) { m2[r] = -1e30f; lsum[r] = 0.f; }
#pragma unroll
  for (int i = 0; i < 4; i++) acc_o[i] = (f32x4){0.f, 0.f, 0.f, 0.f};

  // prologue: stage tile 0 into buf 0 (conflict-free: 64 lanes -> 32 consecutive dwords)
#pragma unroll
  for (int i = 0; i < 2; i++) {
    int hd0 = shb + i * 32;
    bf16x8 vv = *(const bf16x8*)(v + base + (size_t)skv * HD + hd0);
#pragma unroll
    for (int j = 0; j < 8; j++) Vt[0][hd0 + j][skv] = ((ushort)vv[j]);
  }

  for (int tile = 0; tile < SEQ / 64; tile++) {
    const int kv0 = tile * 64;
    const int cur = tile & 1;
    __syncthreads();  // staging of buf[cur] complete; prev reads of buf[cur^1] done

    // stage next tile into buf[cur^1]
    if (tile + 1 < SEQ / 64) {
      const int kvn = kv0 + 64;
#pragma unroll
      for (int i = 0; i < 2; i++) {
        int hd0 = shb + i * 32;
        bf16x8 vv = *(const bf16x8*)(v + base + (size_t)(kvn + skv) * HD + hd0);
#pragma unroll
        for (int j = 0; j < 8; j++) Vt[cur ^ 1][hd0 + j][skv] = ((ushort)vv[j]);
      }
    }

    // QK^T: scores[16 q][64 kv] per wave, K read straight from global (L2-resident)
    f32x4 sc[4];
#pragma unroll
    for (int nb = 0; nb < 4; nb++) sc[nb] = (f32x4){0.f, 0.f, 0.f, 0.f};
#pragma unroll
    for (int nb = 0; nb < 4; nb++) {
#pragma unroll
      for (int kk = 0; kk < 2; kk++) {
        bf16x8 bk = *(const bf16x8*)(k + base + (size_t)(kv0 + nb * 16 + lr) * HD + kk * 32 + lhi * 8);
        sc[nb] = __builtin_amdgcn_mfma_f32_16x16x32_bf16(aq[kk], bk, sc[nb], 0, 0, 0);
      }
    }

    // online softmax in exp2 domain, defer-max (THR=8 -> P bounded by 256)
    float tm2[4];
    bool need = false;
#pragma unroll
    for (int r = 0; r < 4; r++) {
      float tm = fmaxf(fmaxf(sc[0][r], sc[1][r]), fmaxf(sc[2][r], sc[3][r])) * C2EXP;
#pragma unroll
      for (int off = 1; off < 16; off <<= 1) tm = fmaxf(tm, __shfl_xor(tm, off));
      tm2[r] = tm;
      need = need || (tm > m2[r] + 8.f);
    }
    if (__any(need)) {
#pragma unroll
      for (int r = 0; r < 4; r++) {
        float mn = fmaxf(m2[r], tm2[r]);
        float alpha = EXP2F(m2[r] - mn);
        lsum[r] *= alpha;
        m2[r] = mn;
#pragma unroll
        for (int nbh = 0; nbh < 4; nbh++) acc_o[nbh][r] *= alpha;
      }
    }
    float p[4][4];
#pragma unroll
    for (int r = 0; r < 4; r++) {
      float rs = 0.f;
#pragma unroll
      for (int nb = 0; nb < 4; nb++) {
        float pp = EXP2F(sc[nb][r] * C2EXP - m2[r]);
        p[nb][r] = pp;
        rs += pp;
      }
#pragma unroll
      for (int off = 1; off < 16; off <<= 1) rs += __shfl_xor(rs, off);
      lsum[r] += rs;
    }

    // P (bf16) -> per-wave LDS, then PV MFMA (no barrier: Pl is wave-private)
#pragma unroll
    for (int nb = 0; nb < 4; nb++)
#pragma unroll
      for (int r = 0; r < 4; r++)
        Pl[w][lhi * 4 + r][nb * 16 + lr] = f2bf(p[nb][r]);

    bf16x8 ap[2];
#pragma unroll
    for (int kk = 0; kk < 2; kk++) ap[kk] = *(const bf16x8*)(&Pl[w][lr][kk * 32 + lhi * 8]);
#pragma unroll
    for (int nbh = 0; nbh < 4; nbh++) {
#pragma unroll
      for (int kk = 0; kk < 2; kk++) {
        bf16x8 bv = *(const bf16x8*)(&Vt[cur][nbh * 16 + lr][kk * 32 + lhi * 8]);
        acc_o[nbh] = __builtin_amdgcn_mfma_f32_16x16x32_bf16(ap[kk], bv, acc_o[nbh], 0, 0, 0);
      }
    }
  }

  // epilogue: out[b][s][h*64+hd] = acc/l
  const int b = bh >> 4, h = bh & 15;
#pragma unroll
  for (int nbh = 0; nbh < 4; nbh++) {
#pragma unroll
    for (int r = 0; r < 4; r++) {
      int s = q0 + w * 16 + lhi * 4 + r;
      float vv = acc_o[nbh][r] / lsum[r];
      out[((size_t)(b * SEQ + s)) * DMODEL + h * HD + nbh * 16 + lr] = vv;
    }
  }
}

extern "C" void kernel_launch(void* const* d_in, const int* in_sizes, int n_in,
                              void* d_out, int out_size, void* d_ws, size_t ws_size,
                              hipStream_t stream) {
  const float* query = (const float*)d_in[0];
  const float* key_  = (const float*)d_in[1];
  const float* value = (const float*)d_in[2];
  const float* Wq = (const float*)d_in[3];
  const float* bq = (const float*)d_in[4];
  const float* Wk = (const float*)d_in[5];
  const float* bk = (const float*)d_in[6];
  const float* Wv = (const float*)d_in[7];
  const float* bv = (const float*)d_in[8];

  ushort* Wb = (ushort*)d_ws;                       // 3 * 1M bf16
  ushort* qkv = Wb + 3u * 1048576u;                 // 3 * 8.39M bf16

  convert_w<<<dim3(1024, 3), 256, 0, stream>>>(Wq, Wk, Wv, Wb);
  qkv_gemm<<<dim3(64, 8, 3), 256, 0, stream>>>(query, key_, value, Wb, bq, bk, bv, qkv);
  attn_kernel<<<dim3(BHTOT * (SEQ / 64)), 256, 0, stream>>>(qkv, (float*)d_out);
}

// Round 3
// 418.989 us; speedup vs baseline: 1.0356x; 1.0356x over previous
//
#include <hip/hip_runtime.h>
#include <hip/hip_bf16.h>

typedef __attribute__((ext_vector_type(8))) short bf16x8;
typedef __attribute__((ext_vector_type(4))) float f32x4;

#define SEQ 2048
#define DMODEL 1024
#define NH 16
#define HD 64
#define BATCH 4
#define BHTOT 64          // BATCH*NH
#define BS 8192           // BATCH*SEQ
#define QKV_ELEMS 8388608 // BS*DMODEL

// SCALE = 8 (sqrt(64)); softmax done in exp2 domain: C2 = (1/8)*log2(e)
#define C2EXP 0.1803368801111244f

__device__ __forceinline__ ushort f2bf(float f) {
  union { float f; unsigned u; } v; v.f = f;
  unsigned r = (v.u + 0x7FFFu + ((v.u >> 16) & 1u)) >> 16;
  return (ushort)r;
}

#if __has_builtin(__builtin_amdgcn_exp2f)
#define EXP2F(x) __builtin_amdgcn_exp2f(x)
#else
#define EXP2F(x) exp2f(x)
#endif

// ---------------- weight f32 -> bf16 convert ----------------
__global__ __launch_bounds__(256) void convert_w(
    const float* __restrict__ w0, const float* __restrict__ w1,
    const float* __restrict__ w2, ushort* __restrict__ out) {
  const float* src = blockIdx.y == 0 ? w0 : (blockIdx.y == 1 ? w1 : w2);
  size_t e = ((size_t)blockIdx.x * 256 + threadIdx.x) * 4;
  float4 v = *(const float4*)(src + e);
  ushort4 o = { f2bf(v.x), f2bf(v.y), f2bf(v.z), f2bf(v.w) };
  *(ushort4*)(out + (size_t)blockIdx.y * 1048576 + e) = o;
}

// ---------------- QKV projection GEMM ----------------
// out[m][n] = sum_k X[m][k] * W[n][k] + bias[n], stored bf16 in [B,H,S,HD]
__global__ __launch_bounds__(256) void qkv_gemm(
    const float* __restrict__ x0, const float* __restrict__ x1, const float* __restrict__ x2,
    const ushort* __restrict__ Wb,
    const float* __restrict__ bq, const float* __restrict__ bk, const float* __restrict__ bv,
    ushort* __restrict__ qkv) {
  __shared__ ushort sA[128][40];  // +8 pad: row stride 80B -> 2-way bank alias (free)
  __shared__ ushort sB[128][40];

  const int z = blockIdx.z;
  const float* X = z == 0 ? x0 : (z == 1 ? x1 : x2);
  const ushort* W = Wb + (size_t)z * 1048576;
  const float* bias = z == 0 ? bq : (z == 1 ? bk : bv);
  ushort* out = qkv + (size_t)z * QKV_ELEMS;

  const int t = threadIdx.x;
  const int m0 = blockIdx.x * 128;
  const int n0 = blockIdx.y * 128;
  const int w = t >> 6, l = t & 63, lr = l & 15, lhi = l >> 4;
  const int wr = (w >> 1) * 64, wc = (w & 1) * 64;

  f32x4 acc[4][4];
#pragma unroll
  for (int i = 0; i < 4; i++)
#pragma unroll
    for (int j = 0; j < 4; j++) acc[i][j] = (f32x4){0.f, 0.f, 0.f, 0.f};

  for (int k0 = 0; k0 < DMODEL; k0 += 32) {
#pragma unroll
    for (int i = 0; i < 4; i++) {
      int e = i * 256 + t;
      int row = e >> 3, col = (e & 7) * 4;
      float4 a = *(const float4*)(X + (size_t)(m0 + row) * DMODEL + k0 + col);
      ushort4 ab = { f2bf(a.x), f2bf(a.y), f2bf(a.z), f2bf(a.w) };
      *(ushort4*)(&sA[row][col]) = ab;
      ushort4 bb = *(const ushort4*)(W + (size_t)(n0 + row) * DMODEL + k0 + col);
      *(ushort4*)(&sB[row][col]) = bb;
    }
    __syncthreads();
    bf16x8 af[4], bfr[4];
#pragma unroll
    for (int mi = 0; mi < 4; mi++) af[mi] = *(const bf16x8*)(&sA[wr + mi * 16 + lr][lhi * 8]);
#pragma unroll
    for (int ni = 0; ni < 4; ni++) bfr[ni] = *(const bf16x8*)(&sB[wc + ni * 16 + lr][lhi * 8]);
#pragma unroll
    for (int mi = 0; mi < 4; mi++)
#pragma unroll
      for (int ni = 0; ni < 4; ni++)
        acc[mi][ni] = __builtin_amdgcn_mfma_f32_16x16x32_bf16(af[mi], bfr[ni], acc[mi][ni], 0, 0, 0);
    __syncthreads();
  }

  // epilogue: C layout col=lane&15, row=(lane>>4)*4+reg
#pragma unroll
  for (int mi = 0; mi < 4; mi++) {
#pragma unroll
    for (int ni = 0; ni < 4; ni++) {
      int col = n0 + wc + ni * 16 + lr;
      float bsv = bias[col];
      int h = col >> 6, hd = col & 63;
#pragma unroll
      for (int r = 0; r < 4; r++) {
        int row = m0 + wr + mi * 16 + lhi * 4 + r;
        int b = row >> 11, s = row & 2047;
        float vv = acc[mi][ni][r] + bsv;
        out[(((size_t)(b * NH + h)) * SEQ + s) * HD + hd] = f2bf(vv);
      }
    }
  }
}

// ---------------- flash attention ----------------
// qkv: bf16 [3][BH][SEQ][HD]; out: f32 [B,S,D]
// Swapped QK^T: S^T = mfma(K_frag, Q_frag) so each lane's 16 scores belong to ONE
// q row (q = lane&15) -> in-lane softmax reduce + 2 shfl_xor, scalar m/lsum state,
// packed-u32 P writes to wave-private LDS, standard PV keeps coalesced epilogue.
__global__ __launch_bounds__(256) void attn_kernel(const ushort* __restrict__ qkv,
                                                   float* __restrict__ out) {
  __shared__ ushort Vt[2][64][72];   // double-buffered V^T tile: [hd][kv], stride 144B
  __shared__ unsigned Pl[4][16 * 36]; // per-wave P: [q][kv-pairs], row stride 144B

  const int bid = blockIdx.x;
  const int bh = bid >> 5, qt = bid & 31;
  const int q0 = qt * 64;
  const int t = threadIdx.x, w = t >> 6, l = t & 63, lr = l & 15, lhi = l >> 4;

  const ushort* q = qkv;
  const ushort* k = qkv + QKV_ELEMS;
  const ushort* v = qkv + 2 * (size_t)QKV_ELEMS;
  const size_t base = (size_t)bh * SEQ * HD;
  unsigned* Plw = &Pl[w][0];

  // staging coords: each thread loads 16B of one V row, writes a column run
  const int skv = t & 63;        // kv row this thread loads
  const int shb = (t >> 6) * 8;  // hd block base (0,8,16,24), +32 on 2nd iter

  // hoist Q fragments (B-frag: col=q=l&15, k=(l>>4)*8..+8)
  bf16x8 aq[2];
  {
    int qrow = q0 + w * 16 + lr;
#pragma unroll
    for (int kk = 0; kk < 2; kk++)
      aq[kk] = *(const bf16x8*)(q + base + (size_t)qrow * HD + kk * 32 + lhi * 8);
  }

  float m2 = -1e30f, lsum = 0.f;   // per-q (q = lr) state, replicated across lhi
  f32x4 acc_o[4];
#pragma unroll
  for (int i = 0; i < 4; i++) acc_o[i] = (f32x4){0.f, 0.f, 0.f, 0.f};

  // prologue: stage tile 0 into buf 0 (conflict-free: 64 lanes -> 32 consecutive dwords)
#pragma unroll
  for (int i = 0; i < 2; i++) {
    int hd0 = shb + i * 32;
    bf16x8 vv = *(const bf16x8*)(v + base + (size_t)skv * HD + hd0);
#pragma unroll
    for (int j = 0; j < 8; j++) Vt[0][hd0 + j][skv] = ((ushort)vv[j]);
  }

  for (int tile = 0; tile < SEQ / 64; tile++) {
    const int kv0 = tile * 64;
    const int cur = tile & 1;
    __syncthreads();  // staging of buf[cur] complete; prev reads of buf[cur^1] done

    // stage next tile into buf[cur^1]
    if (tile + 1 < SEQ / 64) {
      const int kvn = kv0 + 64;
#pragma unroll
      for (int i = 0; i < 2; i++) {
        int hd0 = shb + i * 32;
        bf16x8 vv = *(const bf16x8*)(v + base + (size_t)(kvn + skv) * HD + hd0);
#pragma unroll
        for (int j = 0; j < 8; j++) Vt[cur ^ 1][hd0 + j][skv] = ((ushort)vv[j]);
      }
    }

    // QK^T (swapped): sc[nb][r] = S[q=lr][kv=nb*16+lhi*4+r] ; K frags from global (L2)
    f32x4 sc[4];
#pragma unroll
    for (int nb = 0; nb < 4; nb++) sc[nb] = (f32x4){0.f, 0.f, 0.f, 0.f};
#pragma unroll
    for (int nb = 0; nb < 4; nb++) {
#pragma unroll
      for (int kk = 0; kk < 2; kk++) {
        bf16x8 bk = *(const bf16x8*)(k + base + (size_t)(kv0 + nb * 16 + lr) * HD + kk * 32 + lhi * 8);
        sc[nb] = __builtin_amdgcn_mfma_f32_16x16x32_bf16(bk, aq[kk], sc[nb], 0, 0, 0);
      }
    }

    // online softmax: in-lane partial max (one q row) + 2 shfl_xor across lhi
    float tm = sc[0][0];
#pragma unroll
    for (int nb = 0; nb < 4; nb++)
#pragma unroll
      for (int r = 0; r < 4; r++) tm = fmaxf(tm, sc[nb][r]);
    tm *= C2EXP;
    tm = fmaxf(tm, __shfl_xor(tm, 16));
    tm = fmaxf(tm, __shfl_xor(tm, 32));
    if (__any(tm > m2 + 8.f)) {   // defer-max: P bounded by 2^8
      float mn = fmaxf(m2, tm);
      float alpha = EXP2F(m2 - mn);
      m2 = mn;
      lsum *= alpha;
#pragma unroll
      for (int r = 0; r < 4; r++) {
        float ar = __shfl(alpha, (lhi << 4) | (lhi * 4 + r));  // alpha of q=lhi*4+r
#pragma unroll
        for (int nbh = 0; nbh < 4; nbh++) acc_o[nbh][r] *= ar;
      }
    }

    // P = exp2(sc*C2 - m2), packed to bf16 pairs in-register
    float rs = 0.f;
    unsigned pk[8];
#pragma unroll
    for (int nb = 0; nb < 4; nb++) {
#pragma unroll
      for (int h = 0; h < 2; h++) {
        float p0 = EXP2F(sc[nb][2 * h] * C2EXP - m2);
        float p1 = EXP2F(sc[nb][2 * h + 1] * C2EXP - m2);
        rs += p0 + p1;
        pk[nb * 2 + h] = (unsigned)f2bf(p0) | ((unsigned)f2bf(p1) << 16);
      }
    }
    rs += __shfl_xor(rs, 16);
    rs += __shfl_xor(rs, 32);
    lsum += rs;

    // P -> wave-private LDS (8 packed u32 writes, ~2-way bank alias)
#pragma unroll
    for (int nb = 0; nb < 4; nb++)
#pragma unroll
      for (int h = 0; h < 2; h++)
        Plw[lr * 36 + nb * 8 + lhi * 2 + h] = pk[nb * 2 + h];

    // PV: O += P * V  (A=P from Plw, B=V^T from Vt; output col=hd, row=q)
    bf16x8 ap[2];
#pragma unroll
    for (int kk = 0; kk < 2; kk++)
      ap[kk] = *(const bf16x8*)(Plw + lr * 36 + kk * 16 + lhi * 4);
#pragma unroll
    for (int nbh = 0; nbh < 4; nbh++) {
#pragma unroll
      for (int kk = 0; kk < 2; kk++) {
        bf16x8 bv = *(const bf16x8*)(&Vt[cur][nbh * 16 + lr][kk * 32 + lhi * 8]);
        acc_o[nbh] = __builtin_amdgcn_mfma_f32_16x16x32_bf16(ap[kk], bv, acc_o[nbh], 0, 0, 0);
      }
    }
  }

  // epilogue: out[b][s][h*64+hd] = acc/lsum(q-row)
  const int b = bh >> 4, h = bh & 15;
  float inv[4];
#pragma unroll
  for (int r = 0; r < 4; r++) {
    float ls = __shfl(lsum, (lhi << 4) | (lhi * 4 + r));  // lsum of q=lhi*4+r
    inv[r] = 1.f / ls;
  }
#pragma unroll
  for (int nbh = 0; nbh < 4; nbh++) {
#pragma unroll
    for (int r = 0; r < 4; r++) {
      int s = q0 + w * 16 + lhi * 4 + r;
      out[((size_t)(b * SEQ + s)) * DMODEL + h * HD + nbh * 16 + lr] = acc_o[nbh][r] * inv[r];
    }
  }
}

extern "C" void kernel_launch(void* const* d_in, const int* in_sizes, int n_in,
                              void* d_out, int out_size, void* d_ws, size_t ws_size,
                              hipStream_t stream) {
  const float* query = (const float*)d_in[0];
  const float* key_  = (const float*)d_in[1];
  const float* value = (const float*)d_in[2];
  const float* Wq = (const float*)d_in[3];
  const float* bq = (const float*)d_in[4];
  const float* Wk = (const float*)d_in[5];
  const float* bk = (const float*)d_in[6];
  const float* Wv = (const float*)d_in[7];
  const float* bv = (const float*)d_in[8];

  ushort* Wb = (ushort*)d_ws;                       // 3 * 1M bf16
  ushort* qkv = Wb + 3u * 1048576u;                 // 3 * 8.39M bf16

  convert_w<<<dim3(1024, 3), 256, 0, stream>>>(Wq, Wk, Wv, Wb);
  qkv_gemm<<<dim3(64, 8, 3), 256, 0, stream>>>(query, key_, value, Wb, bq, bk, bv, qkv);
  attn_kernel<<<dim3(BHTOT * (SEQ / 64)), 256, 0, stream>>>(qkv, (float*)d_out);
}